// Round 1
// baseline (1464.587 us; speedup 1.0000x reference)
//
#include <hip/hip_runtime.h>

namespace {

constexpr int Bb = 8, Cc = 32, Nn = 512, Tt = 24;
constexpr int NSUP = 3;
constexpr int RB = 32;            // rows per S-block
constexpr int NBLK = Nn / RB;     // 16
constexpr int THREADS = 512;
constexpr float K2 = 0.25508681187f;  // (1/sqrt(32)) * log2(e)

__device__ __forceinline__ unsigned int f32_to_bf16_rne(float f) {
  unsigned int u = __float_as_uint(f);
  return (u + 0x7fffu + ((u >> 16) & 1u)) >> 16;
}

#define X2_STEP(avv, kk)                                                    \
  {                                                                         \
    const float4* xr4 = reinterpret_cast<const float4*>(SC + (kk) * 32);    \
    _Pragma("unroll") for (int u4 = 0; u4 < 8; ++u4) {                      \
      const float4 xv = xr4[u4];                                            \
      x2a[u4 * 4 + 0] = fmaf(avv, xv.x, x2a[u4 * 4 + 0]);                   \
      x2a[u4 * 4 + 1] = fmaf(avv, xv.y, x2a[u4 * 4 + 1]);                   \
      x2a[u4 * 4 + 2] = fmaf(avv, xv.z, x2a[u4 * 4 + 2]);                   \
      x2a[u4 * 4 + 3] = fmaf(avv, xv.w, x2a[u4 * 4 + 3]);                   \
    }                                                                       \
  }

__global__ __launch_bounds__(THREADS, 2)
void mgcn_kernel(const float* __restrict__ x,
                 const float* __restrict__ A0,
                 const float* __restrict__ A1g,
                 const float* __restrict__ A2,
                 const float* __restrict__ W,
                 const float* __restrict__ bias,
                 float* __restrict__ out) {
  // LDS: [0,16384) Xt f32 [32][512] ; [16384,32768) SC staging/scratch/x1f32 ;
  //      bytes [131072,163840) X1 bf16 packed as uint [512][16]
  extern __shared__ float lds[];
  float* Xt = lds;
  float* SC = lds + 16384;
  unsigned int* X1u = reinterpret_cast<unsigned int*>(lds + 32768);

  const int bt = blockIdx.x;
  const int b = bt / Tt;
  const int t = bt - b * Tt;
  const int tid = threadIdx.x;
  const int lane = tid & 63;
  const int wave = tid >> 6;

  const float* xb = x + (size_t)b * Cc * Nn * Tt + t;

  // ---- stage Xt[c][v] = x[b,c,v,t]
  {
    const int c = tid & 31;
    const int q = tid >> 5;  // 0..15
    #pragma unroll 4
    for (int i = 0; i < 32; ++i) {
      const int v = q * 32 + i;
      Xt[c * Nn + v] = xb[(size_t)(c * Nn + v) * Tt];
    }
  }
  __syncthreads();

  // ---- y0 contribution (W[:,0:32] @ x)
  float yacc[32];
  {
    float xr[32];
    #pragma unroll
    for (int c = 0; c < 32; ++c) xr[c] = Xt[c * Nn + tid];
    #pragma unroll
    for (int o = 0; o < 32; ++o) {
      float acc = 0.f;
      #pragma unroll
      for (int c = 0; c < 32; ++c) acc = fmaf(W[o * 224 + c], xr[c], acc);
      yacc[o] = acc;
    }
  }

  const float* As[NSUP] = {A0, A1g, A2};

  for (int s = 0; s < NSUP; ++s) {
    const float* a = As[s];

    // ================= x1 = (a .* att) @ X, per 32-row block =================
    for (int blk = 0; blk < NBLK; ++blk) {
      const int wb = blk * RB;
      const int wloc = wave * 4;  // this wave's first row offset within block

      // ---- S rows (raw dot, scaled inside softmax)
      float att[4][8];
      #pragma unroll
      for (int r = 0; r < 4; ++r)
        #pragma unroll
        for (int k = 0; k < 8; ++k) att[r][k] = 0.f;

      for (int c = 0; c < 32; ++c) {
        const float* Xc = Xt + c * Nn;
        const float xw0 = Xc[wb + wloc + 0];
        const float xw1 = Xc[wb + wloc + 1];
        const float xw2 = Xc[wb + wloc + 2];
        const float xw3 = Xc[wb + wloc + 3];
        #pragma unroll
        for (int k = 0; k < 8; ++k) {
          const float xv = Xc[k * 64 + lane];
          att[0][k] = fmaf(xw0, xv, att[0][k]);
          att[1][k] = fmaf(xw1, xv, att[1][k]);
          att[2][k] = fmaf(xw2, xv, att[2][k]);
          att[3][k] = fmaf(xw3, xv, att[3][k]);
        }
      }

      // ---- softmax per row (wave-wide shuffle reduce)
      #pragma unroll
      for (int r = 0; r < 4; ++r) {
        float m = att[r][0];
        #pragma unroll
        for (int k = 1; k < 8; ++k) m = fmaxf(m, att[r][k]);
        #pragma unroll
        for (int off = 32; off >= 1; off >>= 1) m = fmaxf(m, __shfl_xor(m, off));
        float sum = 0.f;
        #pragma unroll
        for (int k = 0; k < 8; ++k) {
          const float e = exp2f((att[r][k] - m) * K2);
          att[r][k] = e;
          sum += e;
        }
        #pragma unroll
        for (int off = 32; off >= 1; off >>= 1) sum += __shfl_xor(sum, off);
        const float inv = 1.f / sum;
        #pragma unroll
        for (int k = 0; k < 8; ++k) att[r][k] *= inv;
      }

      // ---- A1 staging = att * a   (xor-swizzled [v][w32])
      #pragma unroll
      for (int r = 0; r < 4; ++r) {
        const int wrow = wb + wloc + r;
        const float* arow = a + (size_t)wrow * Nn;
        #pragma unroll
        for (int k = 0; k < 8; ++k) {
          const int v = k * 64 + lane;
          SC[v * 32 + ((wloc + r) ^ (v & 31))] = att[r][k] * arow[v];
        }
      }
      __syncthreads();

      // ---- x1 block GEMM, split-K per wave (wave g owns v in [64g,64g+64))
      {
        const int wcol = lane & 31;
        const int ch = lane >> 5;
        float pacc[16];
        #pragma unroll
        for (int u = 0; u < 16; ++u) pacc[u] = 0.f;
        const int v0 = wave * 64;
        #pragma unroll 4
        for (int vi = 0; vi < 64; ++vi) {
          const int v = v0 + vi;
          const float av = SC[v * 32 + (wcol ^ (v & 31))];
          #pragma unroll
          for (int u = 0; u < 16; ++u)
            pacc[u] = fmaf(av, Xt[(ch * 16 + u) * Nn + v], pacc[u]);
        }
        __syncthreads();
        // partial scratch: [g][w(33-pad)][c]
        #pragma unroll
        for (int u = 0; u < 16; ++u)
          SC[wave * 1056 + wcol * 33 + ch * 16 + u] = pacc[u];
      }
      __syncthreads();

      // ---- reduce 8 wave-partials -> X1 (bf16 packed)
      {
        const int w = tid >> 4;  // 0..31
        const int q = tid & 15;  // 0..15
        float s0 = 0.f, s1 = 0.f;
        #pragma unroll
        for (int g = 0; g < 8; ++g) {
          s0 += SC[g * 1056 + w * 33 + 2 * q + 0];
          s1 += SC[g * 1056 + w * 33 + 2 * q + 1];
        }
        X1u[(wb + w) * 16 + q] = f32_to_bf16_rne(s0) | (f32_to_bf16_rne(s1) << 16);
      }
      __syncthreads();
    }  // blk

    // ---- y1 contribution + expand x1 (bf16 -> f32 into SC, linear [v][c])
    {
      float xr[32];
      #pragma unroll
      for (int q = 0; q < 16; ++q) {
        const unsigned int u = X1u[tid * 16 + q];
        xr[2 * q + 0] = __uint_as_float(u << 16);
        xr[2 * q + 1] = __uint_as_float(u & 0xffff0000u);
      }
      #pragma unroll
      for (int o = 0; o < 32; ++o) {
        float acc = 0.f;
        #pragma unroll
        for (int c = 0; c < 32; ++c)
          acc = fmaf(W[o * 224 + 32 + 64 * s + c], xr[c], acc);
        yacc[o] += acc;
      }
      __syncthreads();
      #pragma unroll
      for (int u4 = 0; u4 < 8; ++u4) {
        const float4 v4 = make_float4(xr[u4 * 4 + 0], xr[u4 * 4 + 1],
                                      xr[u4 * 4 + 2], xr[u4 * 4 + 3]);
        *reinterpret_cast<float4*>(SC + tid * 32 + u4 * 4) = v4;
      }
    }
    __syncthreads();

    // ---- x2 = a @ x1 (thread-per-row) + y2 contribution
    {
      float x2a[32];
      #pragma unroll
      for (int c = 0; c < 32; ++c) x2a[c] = 0.f;
      const float4* arow = reinterpret_cast<const float4*>(a + (size_t)tid * Nn);
      for (int chunk = 0; chunk < 32; ++chunk) {
        #pragma unroll
        for (int m4 = 0; m4 < 4; ++m4) {
          const float4 a4 = arow[chunk * 4 + m4];
          const int kb = chunk * 16 + m4 * 4;
          X2_STEP(a4.x, kb + 0);
          X2_STEP(a4.y, kb + 1);
          X2_STEP(a4.z, kb + 2);
          X2_STEP(a4.w, kb + 3);
        }
      }
      #pragma unroll
      for (int o = 0; o < 32; ++o) {
        float acc = 0.f;
        #pragma unroll
        for (int c = 0; c < 32; ++c)
          acc = fmaf(W[o * 224 + 64 + 64 * s + c], x2a[c], acc);
        yacc[o] += acc;
      }
    }
    __syncthreads();
  }  // s

  // ---- store out[b][o][n=tid][t] (+bias)
  {
    const size_t base = ((size_t)b * 32) * (Nn * Tt) + (size_t)tid * Tt + t;
    #pragma unroll
    for (int o = 0; o < 32; ++o)
      out[base + (size_t)o * (Nn * Tt)] = yacc[o] + bias[o];
  }
}

}  // namespace

extern "C" void kernel_launch(void* const* d_in, const int* in_sizes, int n_in,
                              void* d_out, int out_size, void* d_ws, size_t ws_size,
                              hipStream_t stream) {
  (void)in_sizes; (void)n_in; (void)d_ws; (void)ws_size; (void)out_size;
  const float* x  = reinterpret_cast<const float*>(d_in[0]);
  const float* a0 = reinterpret_cast<const float*>(d_in[1]);
  const float* a1 = reinterpret_cast<const float*>(d_in[2]);
  const float* a2 = reinterpret_cast<const float*>(d_in[3]);
  const float* W  = reinterpret_cast<const float*>(d_in[4]);
  const float* bb = reinterpret_cast<const float*>(d_in[5]);
  float* out = reinterpret_cast<float*>(d_out);

  static_cast<void>(hipFuncSetAttribute(
      reinterpret_cast<const void*>(mgcn_kernel),
      hipFuncAttributeMaxDynamicSharedMemorySize, 163840));

  mgcn_kernel<<<dim3(Bb * Tt), dim3(THREADS), 163840, stream>>>(
      x, a0, a1, a2, W, bb, out);
}